// Round 6
// baseline (291.946 us; speedup 1.0000x reference)
//
#include <hip/hip_runtime.h>
#include <stdint.h>

#define MDIM 4096
#define NDIM 4096
#define KDIM 4096

#define BM 256
#define BN 256
#define BK 64
#define NT (KDIM / BK)

typedef __attribute__((ext_vector_type(8))) __bf16 bf16x8;
typedef __attribute__((ext_vector_type(4))) float f32x4;
typedef __attribute__((ext_vector_type(8))) unsigned short ushort8_t;
typedef __attribute__((ext_vector_type(4))) unsigned short ushort4_t;

typedef const __attribute__((address_space(1))) void* gas_ptr;
typedef __attribute__((address_space(3))) void* las_ptr;

__device__ __forceinline__ void async_load16(const void* g, void* l) {
    // global -> LDS direct DMA, 16B/lane; LDS dest = wave-uniform base + lane*16
    __builtin_amdgcn_global_load_lds((gas_ptr)g, (las_ptr)l, 16, 0, 0);
}

__device__ __forceinline__ unsigned short f32_to_bf16_rne(float f) {
    union { float f; uint32_t u; } v; v.f = f;
    uint32_t u = v.u;
    return (unsigned short)((u + 0x7FFFu + ((u >> 16) & 1u)) >> 16);
}

__device__ __forceinline__ unsigned short sgn_bf16(float w) {
    return (w > 0.f) ? 0x3F80u : ((w < 0.f) ? 0xBF80u : 0u);
}

// ---------------- fused prep kernel (R2-verified) ----------------

#define XBLKS 2048

__global__ void prep_kernel(const float* __restrict__ x, const float* __restrict__ W,
                            unsigned short* __restrict__ xbf, unsigned short* __restrict__ wqT) {
    if (blockIdx.x < XBLKS) {
        const int tot8 = MDIM * KDIM / 8;
        int t = blockIdx.x * 256 + threadIdx.x;
        const int stride = XBLKS * 256;
        for (int i = t; i < tot8; i += stride) {
            float4 v0 = ((const float4*)x)[2 * i];
            float4 v1 = ((const float4*)x)[2 * i + 1];
            ushort8_t o;
            o[0] = f32_to_bf16_rne(v0.x); o[1] = f32_to_bf16_rne(v0.y);
            o[2] = f32_to_bf16_rne(v0.z); o[3] = f32_to_bf16_rne(v0.w);
            o[4] = f32_to_bf16_rne(v1.x); o[5] = f32_to_bf16_rne(v1.y);
            o[6] = f32_to_bf16_rne(v1.z); o[7] = f32_to_bf16_rne(v1.w);
            ((ushort8_t*)xbf)[i] = o;
        }
    } else {
        __shared__ __align__(16) unsigned short tile[64][68];
        const int wb = blockIdx.x - XBLKS;
        const int n0 = (wb & 63) * 64;
        const int k0 = (wb >> 6) * 64;
        const int t  = threadIdx.x;
#pragma unroll
        for (int r = 0; r < 2; ++r) {
            int flat = r * 256 + t;
            int k2   = flat >> 4;
            int nch  = (flat & 15) * 4;
            const float* s0 = &W[(size_t)(k0 + 2 * k2) * NDIM + n0 + nch];
            float4 v0 = *(const float4*)(s0);
            float4 v1 = *(const float4*)(s0 + NDIM);
            const float* f0 = (const float*)&v0;
            const float* f1 = (const float*)&v1;
#pragma unroll
            for (int j = 0; j < 4; ++j) {
                union { unsigned short u[2]; unsigned int w; } p;
                p.u[0] = sgn_bf16(f0[j]);
                p.u[1] = sgn_bf16(f1[j]);
                *(unsigned int*)&tile[nch + j][2 * k2] = p.w;
            }
        }
        __syncthreads();
#pragma unroll
        for (int r = 0; r < 2; ++r) {
            int flat = r * 256 + t;
            int n    = flat >> 3;
            int kch  = (flat & 7) * 8;
            ushort4_t a = *(const ushort4_t*)&tile[n][kch];
            ushort4_t b = *(const ushort4_t*)&tile[n][kch + 4];
            ushort8_t o;
            o[0] = a[0]; o[1] = a[1]; o[2] = a[2]; o[3] = a[3];
            o[4] = b[0]; o[5] = b[1]; o[6] = b[2]; o[7] = b[3];
            *(ushort8_t*)&wqT[(size_t)(n0 + n) * KDIM + k0 + kch] = o;
        }
    }
}

// ---- GEMM: R2 pipeline + fine-grained per-phase staging (m196/m201 interleave) --
// 256x256 tile, 8 waves, 16x16x32 MFMA, 4 phases/tile, both-sides XOR swizzle,
// boundary vmcnt(8). NEW (R6): tile t+2's 8 DMAs spread 2/4/2 (lo waves) or
// 2/2/4 (hi waves) across ph1/ph2/ph3, with per-wave group reassignment so every
// stage targets bytes whose last reader retired a barrier earlier:
//   waves 0-3: A-early groups (read ph0) + B-late groups (read ph1)
//   waves 4-7: B-early groups (read ph0) + A-late groups (read ph2)
// Race-freedom: phase p's ds_reads all feed phase p's MFMA (lgkm-waited), so they
// retire before the phase-end barrier; stages issue only after that barrier.
// Direct-store epilogue (R2): partial-line RMW traffic is free at <25% HBM util.

__global__ __launch_bounds__(512, 2) void gemm_bf16_bt(
        const unsigned short* __restrict__ A,
        const unsigned short* __restrict__ Bt,
        const float* __restrict__ bias,
        float* __restrict__ C)
{
    __shared__ __align__(16) unsigned short lds[2][2][BM * BK];

    const int tid  = threadIdx.x;
    const int wave = tid >> 6;
    const int lane = tid & 63;
    const int wm = wave >> 2;
    const int wn = wave & 3;

    int o   = blockIdx.y * gridDim.x + blockIdx.x;
    int xcd = o & 7, ii = o >> 3;
    int bmi = (xcd >> 1) * 4 + (ii >> 3);
    int bni = (xcd & 1) * 8 + (ii & 7);
    const int bm = bmi * BM;
    const int bn = bni * BN;

    const int lrow = lane >> 3;
    const int lchk = (lane & 7) ^ lrow;
    const size_t aSrc = (size_t)(bm + lrow) * KDIM + lchk * 8;
    const size_t bSrc = (size_t)(bn + lrow) * KDIM + lchk * 8;

    // staging group assignment (see header):
    //   ag0: waves 0-3 -> {0,4,16,20} (A-early); waves 4-7 -> {8,12,24,28} (A-late)
    //   bg0: waves 0-3 -> {4,12,20,28} (B-late); waves 4-7 -> {0,8,16,24} (B-early)
    const int ag0 = ((wave >> 1) & 1) * 16 + (wave & 1) * 4 + ((wave >> 2) << 3);
    const int bg0 = (wave & 3) * 8 + ((wave >> 2) ? 0 : 4);
    const bool loW = wave < 4;

#define STAGE_A(BUF, TK, G) async_load16(A  + aSrc + (size_t)(G) * (8 * KDIM) + (TK), \
                                         &lds[BUF][0][(G) * 512])
#define STAGE_B(BUF, TK, G) async_load16(Bt + bSrc + (size_t)(G) * (8 * KDIM) + (TK), \
                                         &lds[BUF][1][(G) * 512])

    const int frow = lane & 15;
    const int rb  = frow * 128;
    const int cx0 = ((lane >> 4) ^ (lane & 7)) << 4;
    const int cx1 = cx0 ^ 64;

    const char* L = (const char*)lds;
    const char* aP00 = L +     0 + wm * 16384 + rb + cx0;
    const char* aP01 = L +     0 + wm * 16384 + rb + cx1;
    const char* aP10 = L + 65536 + wm * 16384 + rb + cx0;
    const char* aP11 = L + 65536 + wm * 16384 + rb + cx1;
    const char* bP00 = L + 32768 +         wn * 8192 + rb + cx0;
    const char* bP01 = L + 32768 +         wn * 8192 + rb + cx1;
    const char* bP10 = L + 98304 +         wn * 8192 + rb + cx0;
    const char* bP11 = L + 98304 +         wn * 8192 + rb + cx1;

    f32x4 acc[8][4] = {};
    bf16x8 af[4][2];
    bf16x8 bfr[4][2];

#define MFMA16(MIB, NIB)                                                        \
    _Pragma("unroll")                                                           \
    for (int mi = 0; mi < 4; ++mi)                                              \
        _Pragma("unroll")                                                       \
        for (int ni = 0; ni < 2; ++ni)                                          \
            _Pragma("unroll")                                                   \
            for (int ks = 0; ks < 2; ++ks)                                      \
                acc[(MIB) + mi][(NIB) + ni] =                                   \
                    __builtin_amdgcn_mfma_f32_16x16x32_bf16(                    \
                        af[mi][ks], bfr[(NIB) + ni][ks],                        \
                        acc[(MIB) + mi][(NIB) + ni], 0, 0, 0);

#define STAGE_TILE(BUF, TK)                                                     \
    do {                                                                        \
        STAGE_A(BUF, TK, ag0 + 0); STAGE_A(BUF, TK, ag0 + 1);                   \
        STAGE_A(BUF, TK, ag0 + 2); STAGE_A(BUF, TK, ag0 + 3);                   \
        STAGE_B(BUF, TK, bg0 + 0); STAGE_B(BUF, TK, bg0 + 1);                   \
        STAGE_B(BUF, TK, bg0 + 2); STAGE_B(BUF, TK, bg0 + 3);                   \
    } while (0)

#define STAGE2_PH1(BUF, TK)                                                     \
    do { if (loW) { STAGE_A(BUF, TK, ag0 + 0); STAGE_A(BUF, TK, ag0 + 1); }     \
         else     { STAGE_B(BUF, TK, bg0 + 0); STAGE_B(BUF, TK, bg0 + 1); } } while (0)
#define STAGE4_PH2(BUF, TK)                                                     \
    do { if (loW) { STAGE_A(BUF, TK, ag0 + 2); STAGE_A(BUF, TK, ag0 + 3);       \
                    STAGE_B(BUF, TK, bg0 + 0); STAGE_B(BUF, TK, bg0 + 1); }     \
         else     { STAGE_B(BUF, TK, bg0 + 2); STAGE_B(BUF, TK, bg0 + 3); } } while (0)
#define STAGE2_PH3(BUF, TK)                                                     \
    do { if (loW) { STAGE_B(BUF, TK, bg0 + 2); STAGE_B(BUF, TK, bg0 + 3); }     \
         else     { STAGE_A(BUF, TK, ag0 + 0); STAGE_A(BUF, TK, ag0 + 1);       \
                    STAGE_A(BUF, TK, ag0 + 2); STAGE_A(BUF, TK, ag0 + 3); } } while (0)

    // prologue: tile0 -> buf0, tile1 -> buf1; wait only tile0's 8 loads
    STAGE_TILE(0, 0);
    STAGE_TILE(1, BK);
    asm volatile("s_waitcnt vmcnt(8)" ::: "memory");
    __builtin_amdgcn_s_barrier();
    asm volatile("" ::: "memory");
    __builtin_amdgcn_sched_barrier(0);

    for (int t = 0; t < NT; ++t) {
        const bool odd  = t & 1;
        const char* aK0 = odd ? aP10 : aP00;
        const char* aK1 = odd ? aP11 : aP01;
        const char* bK0 = odd ? bP10 : bP00;
        const char* bK1 = odd ? bP11 : bP01;
        const int  cur  = odd ? 1 : 0;
        const int  tkn  = (t + 2) * BK;
        const bool more = (t + 2 < NT);

        // ---- phase 0: read af(grp0)+bfr(n0,n1); MFMA rows 0-3 x n0,n1 ----
#pragma unroll
        for (int mi = 0; mi < 4; ++mi) {
            af[mi][0] = *(const bf16x8*)(aK0 + mi * 2048);
            af[mi][1] = *(const bf16x8*)(aK1 + mi * 2048);
        }
#pragma unroll
        for (int ni = 0; ni < 2; ++ni) {
            bfr[ni][0] = *(const bf16x8*)(bK0 + ni * 2048);
            bfr[ni][1] = *(const bf16x8*)(bK1 + ni * 2048);
        }
        __builtin_amdgcn_s_barrier();
        __builtin_amdgcn_s_setprio(1);
        MFMA16(0, 0)
        __builtin_amdgcn_s_setprio(0);
        __builtin_amdgcn_s_barrier();

        // ---- phase 1: read bfr(n2,n3); stage 2; MFMA rows 0-3 x n2,n3 ----
#pragma unroll
        for (int ni = 2; ni < 4; ++ni) {
            bfr[ni][0] = *(const bf16x8*)(bK0 + ni * 2048);
            bfr[ni][1] = *(const bf16x8*)(bK1 + ni * 2048);
        }
        if (more) STAGE2_PH1(cur, tkn);
        __builtin_amdgcn_s_barrier();
        __builtin_amdgcn_s_setprio(1);
        MFMA16(0, 2)
        __builtin_amdgcn_s_setprio(0);
        __builtin_amdgcn_s_barrier();

        // ---- phase 2: read af(grp1); stage 4; MFMA rows 4-7 x n2,n3 ----
#pragma unroll
        for (int mi = 0; mi < 4; ++mi) {
            af[mi][0] = *(const bf16x8*)(aK0 + 8192 + mi * 2048);
            af[mi][1] = *(const bf16x8*)(aK1 + 8192 + mi * 2048);
        }
        if (more) STAGE4_PH2(cur, tkn);
        __builtin_amdgcn_s_barrier();
        __builtin_amdgcn_s_setprio(1);
        MFMA16(4, 2)
        __builtin_amdgcn_s_setprio(0);
        __builtin_amdgcn_s_barrier();

        // ---- phase 3: stage 2; MFMA rows 4-7 x n0,n1 ----
        if (more) STAGE2_PH3(cur, tkn);
        __builtin_amdgcn_s_setprio(1);
        MFMA16(4, 0)
        __builtin_amdgcn_s_setprio(0);

        // boundary: retire tile t+1's 8 loads; keep t+2's 8 in flight
        if (more) {
            asm volatile("s_waitcnt vmcnt(8)" ::: "memory");
        } else if (t + 1 < NT) {
            asm volatile("s_waitcnt vmcnt(0)" ::: "memory");
        }
        if (t + 1 < NT) {
            __builtin_amdgcn_s_barrier();
            asm volatile("" ::: "memory");
            __builtin_amdgcn_sched_barrier(0);
        }
    }

    // ---- epilogue (R2 direct stores): col=lane&15, row=(lane>>4)*4+reg ----
#pragma unroll
    for (int ni = 0; ni < 4; ++ni) {
        int col = bn + wn * 64 + ni * 16 + frow;
        float bv = bias[col];
#pragma unroll
        for (int mig = 0; mig < 8; ++mig) {
            int row0 = bm + wm * 128 + mig * 16 + (lane >> 4) * 4;
#pragma unroll
            for (int r = 0; r < 4; ++r)
                C[(size_t)(row0 + r) * NDIM + col] = acc[mig][ni][r] + bv;
        }
    }
#undef STAGE_A
#undef STAGE_B
#undef STAGE_TILE
#undef STAGE2_PH1
#undef STAGE4_PH2
#undef STAGE2_PH3
#undef MFMA16
}

// ---------------- fallback ----------------

__global__ void fallback_gemm(const float* __restrict__ x, const float* __restrict__ W,
                              const float* __restrict__ b, float* __restrict__ out) {
    __shared__ float As[32][32];
    __shared__ float Bs[32][33];
    int tx = threadIdx.x, ty = threadIdx.y;
    int row = blockIdx.y * 32 + ty;
    int col = blockIdx.x * 32 + tx;
    float acc = 0.0f;
    for (int kt = 0; kt < KDIM; kt += 32) {
        As[ty][tx] = x[(size_t)row * KDIM + kt + tx];
        float w = W[(size_t)(kt + ty) * NDIM + col];
        Bs[ty][tx] = (w > 0.0f) ? 1.0f : ((w < 0.0f) ? -1.0f : 0.0f);
        __syncthreads();
#pragma unroll
        for (int k = 0; k < 32; ++k) acc += As[ty][k] * Bs[k][tx];
        __syncthreads();
    }
    out[(size_t)row * NDIM + col] = acc + b[col];
}

extern "C" void kernel_launch(void* const* d_in, const int* in_sizes, int n_in,
                              void* d_out, int out_size, void* d_ws, size_t ws_size,
                              hipStream_t stream) {
    const float* x = (const float*)d_in[0];
    const float* W = (const float*)d_in[1];
    const float* b = (const float*)d_in[2];
    float* out = (float*)d_out;

    const size_t need = (size_t)MDIM * KDIM * 2 + (size_t)KDIM * NDIM * 2;
    if (ws_size >= need) {
        unsigned short* xbf = (unsigned short*)d_ws;
        unsigned short* wqT = xbf + (size_t)MDIM * KDIM;
        prep_kernel<<<XBLKS + (NDIM / 64) * (KDIM / 64), 256, 0, stream>>>(x, W, xbf, wqT);
        gemm_bf16_bt<<<dim3(NDIM / BN, MDIM / BM), 512, 0, stream>>>(xbf, wqT, b, out);
    } else {
        fallback_gemm<<<dim3(NDIM / 32, MDIM / 32), dim3(32, 32), 0, stream>>>(x, W, b, out);
    }
}

// Round 7
// 281.209 us; speedup vs baseline: 1.0382x; 1.0382x over previous
//
#include <hip/hip_runtime.h>
#include <stdint.h>

#define MDIM 4096
#define NDIM 4096
#define KDIM 4096

#define BM 256
#define BN 256
#define BK 64
#define NT (KDIM / BK)

typedef __attribute__((ext_vector_type(8))) __bf16 bf16x8;
typedef __attribute__((ext_vector_type(4))) float f32x4;
typedef __attribute__((ext_vector_type(8))) unsigned short ushort8_t;
typedef __attribute__((ext_vector_type(4))) unsigned short ushort4_t;

typedef const __attribute__((address_space(1))) void* gas_ptr;
typedef __attribute__((address_space(3))) void* las_ptr;

__device__ __forceinline__ void async_load16(const void* g, void* l) {
    // global -> LDS direct DMA, 16B/lane; LDS dest = wave-uniform base + lane*16
    __builtin_amdgcn_global_load_lds((gas_ptr)g, (las_ptr)l, 16, 0, 0);
}

__device__ __forceinline__ unsigned short f32_to_bf16_rne(float f) {
    union { float f; uint32_t u; } v; v.f = f;
    uint32_t u = v.u;
    return (unsigned short)((u + 0x7FFFu + ((u >> 16) & 1u)) >> 16);
}

__device__ __forceinline__ unsigned short sgn_bf16(float w) {
    return (w > 0.f) ? 0x3F80u : ((w < 0.f) ? 0xBF80u : 0u);
}

// ---------------- fused prep kernel (R2-verified) ----------------

#define XBLKS 2048

__global__ void prep_kernel(const float* __restrict__ x, const float* __restrict__ W,
                            unsigned short* __restrict__ xbf, unsigned short* __restrict__ wqT) {
    if (blockIdx.x < XBLKS) {
        const int tot8 = MDIM * KDIM / 8;
        int t = blockIdx.x * 256 + threadIdx.x;
        const int stride = XBLKS * 256;
        for (int i = t; i < tot8; i += stride) {
            float4 v0 = ((const float4*)x)[2 * i];
            float4 v1 = ((const float4*)x)[2 * i + 1];
            ushort8_t o;
            o[0] = f32_to_bf16_rne(v0.x); o[1] = f32_to_bf16_rne(v0.y);
            o[2] = f32_to_bf16_rne(v0.z); o[3] = f32_to_bf16_rne(v0.w);
            o[4] = f32_to_bf16_rne(v1.x); o[5] = f32_to_bf16_rne(v1.y);
            o[6] = f32_to_bf16_rne(v1.z); o[7] = f32_to_bf16_rne(v1.w);
            ((ushort8_t*)xbf)[i] = o;
        }
    } else {
        __shared__ __align__(16) unsigned short tile[64][68];
        const int wb = blockIdx.x - XBLKS;
        const int n0 = (wb & 63) * 64;
        const int k0 = (wb >> 6) * 64;
        const int t  = threadIdx.x;
#pragma unroll
        for (int r = 0; r < 2; ++r) {
            int flat = r * 256 + t;
            int k2   = flat >> 4;
            int nch  = (flat & 15) * 4;
            const float* s0 = &W[(size_t)(k0 + 2 * k2) * NDIM + n0 + nch];
            float4 v0 = *(const float4*)(s0);
            float4 v1 = *(const float4*)(s0 + NDIM);
            const float* f0 = (const float*)&v0;
            const float* f1 = (const float*)&v1;
#pragma unroll
            for (int j = 0; j < 4; ++j) {
                union { unsigned short u[2]; unsigned int w; } p;
                p.u[0] = sgn_bf16(f0[j]);
                p.u[1] = sgn_bf16(f1[j]);
                *(unsigned int*)&tile[nch + j][2 * k2] = p.w;
            }
        }
        __syncthreads();
#pragma unroll
        for (int r = 0; r < 2; ++r) {
            int flat = r * 256 + t;
            int n    = flat >> 3;
            int kch  = (flat & 7) * 8;
            ushort4_t a = *(const ushort4_t*)&tile[n][kch];
            ushort4_t b = *(const ushort4_t*)&tile[n][kch + 4];
            ushort8_t o;
            o[0] = a[0]; o[1] = a[1]; o[2] = a[2]; o[3] = a[3];
            o[4] = b[0]; o[5] = b[1]; o[6] = b[2]; o[7] = b[3];
            *(ushort8_t*)&wqT[(size_t)(n0 + n) * KDIM + k0 + kch] = o;
        }
    }
}

// ---- GEMM: R2 pipeline, MINIMAL barriers (R7) ----
// 256x256 tile, 8 waves, 16x16x32 MFMA, both-sides XOR swizzle, coarse ph3
// staging, boundary vmcnt(8). Sync reduced from 7 barriers/tile to 2:
//   (1) mid-tile fence after the last ds_read of buf[cur], before stages
//       (asm memory clobber pins reads above; sched_barrier(0) pins DMAs below)
//   (2) boundary vmcnt(8) + barrier (makes "t+1 data landed" global)
// Within the tile, waves free-run: compiler hoists fragment reads (ILP) and
// emits fine-grained lgkmcnt; cross-wave read/MFMA overlap is now possible.

__global__ __launch_bounds__(512, 2) void gemm_bf16_bt(
        const unsigned short* __restrict__ A,
        const unsigned short* __restrict__ Bt,
        const float* __restrict__ bias,
        float* __restrict__ C)
{
    __shared__ __align__(16) unsigned short lds[2][2][BM * BK];

    const int tid  = threadIdx.x;
    const int wave = tid >> 6;
    const int lane = tid & 63;
    const int wm = wave >> 2;
    const int wn = wave & 3;

    int o   = blockIdx.y * gridDim.x + blockIdx.x;
    int xcd = o & 7, ii = o >> 3;
    int bmi = (xcd >> 1) * 4 + (ii >> 3);
    int bni = (xcd & 1) * 8 + (ii & 7);
    const int bm = bmi * BM;
    const int bn = bni * BN;

    const int lrow = lane >> 3;
    const int lchk = (lane & 7) ^ lrow;
    const size_t aSrc = (size_t)(bm + lrow) * KDIM + lchk * 8;
    const size_t bSrc = (size_t)(bn + lrow) * KDIM + lchk * 8;
    const int g0 = wave * 4;

#define STAGE_A(BUF, TK, G) async_load16(A  + aSrc + (size_t)(G) * (8 * KDIM) + (TK), \
                                         &lds[BUF][0][(G) * 512])
#define STAGE_B(BUF, TK, G) async_load16(Bt + bSrc + (size_t)(G) * (8 * KDIM) + (TK), \
                                         &lds[BUF][1][(G) * 512])

    const int frow = lane & 15;
    const int rb  = frow * 128;
    const int cx0 = ((lane >> 4) ^ (lane & 7)) << 4;
    const int cx1 = cx0 ^ 64;

    const char* L = (const char*)lds;
    const char* aP00 = L +     0 + wm * 16384 + rb + cx0;
    const char* aP01 = L +     0 + wm * 16384 + rb + cx1;
    const char* aP10 = L + 65536 + wm * 16384 + rb + cx0;
    const char* aP11 = L + 65536 + wm * 16384 + rb + cx1;
    const char* bP00 = L + 32768 +         wn * 8192 + rb + cx0;
    const char* bP01 = L + 32768 +         wn * 8192 + rb + cx1;
    const char* bP10 = L + 98304 +         wn * 8192 + rb + cx0;
    const char* bP11 = L + 98304 +         wn * 8192 + rb + cx1;

    f32x4 acc[8][4] = {};
    bf16x8 af[4][2];
    bf16x8 bfr[4][2];

#define MFMA16(MIB, NIB)                                                        \
    _Pragma("unroll")                                                           \
    for (int mi = 0; mi < 4; ++mi)                                              \
        _Pragma("unroll")                                                       \
        for (int ni = 0; ni < 2; ++ni)                                          \
            _Pragma("unroll")                                                   \
            for (int ks = 0; ks < 2; ++ks)                                      \
                acc[(MIB) + mi][(NIB) + ni] =                                   \
                    __builtin_amdgcn_mfma_f32_16x16x32_bf16(                    \
                        af[mi][ks], bfr[(NIB) + ni][ks],                        \
                        acc[(MIB) + mi][(NIB) + ni], 0, 0, 0);

#define STAGE_TILE(BUF, TK)                                      \
    do {                                                         \
        STAGE_A(BUF, TK, g0 + 0); STAGE_A(BUF, TK, g0 + 1);      \
        STAGE_A(BUF, TK, g0 + 2); STAGE_A(BUF, TK, g0 + 3);      \
        STAGE_B(BUF, TK, g0 + 0); STAGE_B(BUF, TK, g0 + 1);      \
        STAGE_B(BUF, TK, g0 + 2); STAGE_B(BUF, TK, g0 + 3);      \
    } while (0)

    // prologue: tile0 -> buf0, tile1 -> buf1; wait only tile0's 8 loads
    STAGE_TILE(0, 0);
    STAGE_TILE(1, BK);
    asm volatile("s_waitcnt vmcnt(8)" ::: "memory");
    __builtin_amdgcn_s_barrier();
    asm volatile("" ::: "memory");
    __builtin_amdgcn_sched_barrier(0);

    for (int t = 0; t < NT; ++t) {
        const bool odd  = t & 1;
        const char* aK0 = odd ? aP10 : aP00;
        const char* aK1 = odd ? aP11 : aP01;
        const char* bK0 = odd ? bP10 : bP00;
        const char* bK1 = odd ? bP11 : bP01;
        const int  cur  = odd ? 1 : 0;

        // ---- free-run region: all reads of buf[cur] + 48 MFMA ----
#pragma unroll
        for (int mi = 0; mi < 4; ++mi) {
            af[mi][0] = *(const bf16x8*)(aK0 + mi * 2048);
            af[mi][1] = *(const bf16x8*)(aK1 + mi * 2048);
        }
#pragma unroll
        for (int ni = 0; ni < 2; ++ni) {
            bfr[ni][0] = *(const bf16x8*)(bK0 + ni * 2048);
            bfr[ni][1] = *(const bf16x8*)(bK1 + ni * 2048);
        }
        __builtin_amdgcn_s_setprio(1);
        MFMA16(0, 0)
        __builtin_amdgcn_s_setprio(0);

#pragma unroll
        for (int ni = 2; ni < 4; ++ni) {
            bfr[ni][0] = *(const bf16x8*)(bK0 + ni * 2048);
            bfr[ni][1] = *(const bf16x8*)(bK1 + ni * 2048);
        }
        __builtin_amdgcn_s_setprio(1);
        MFMA16(0, 2)
        __builtin_amdgcn_s_setprio(0);

#pragma unroll
        for (int mi = 0; mi < 4; ++mi) {
            af[mi][0] = *(const bf16x8*)(aK0 + 8192 + mi * 2048);
            af[mi][1] = *(const bf16x8*)(aK1 + 8192 + mi * 2048);
        }
        __builtin_amdgcn_s_setprio(1);
        MFMA16(4, 2)
        __builtin_amdgcn_s_setprio(0);

        // ---- mid-tile fence: all waves' reads of buf[cur] done; stages below ----
        asm volatile("" ::: "memory");          // pin ds_reads above
        __builtin_amdgcn_s_barrier();
        __builtin_amdgcn_sched_barrier(0);      // pin DMA stages below

        if (t + 2 < NT) {
            STAGE_TILE(cur, (t + 2) * BK);
        }
        __builtin_amdgcn_s_setprio(1);
        MFMA16(4, 0)
        __builtin_amdgcn_s_setprio(0);

        // ---- boundary: retire t+1's 8 loads; keep t+2's 8 in flight ----
        if (t + 2 < NT) {
            asm volatile("s_waitcnt vmcnt(8)" ::: "memory");
        } else if (t + 1 < NT) {
            asm volatile("s_waitcnt vmcnt(0)" ::: "memory");
        }
        if (t + 1 < NT) {
            __builtin_amdgcn_s_barrier();
            asm volatile("" ::: "memory");
            __builtin_amdgcn_sched_barrier(0);
        }
    }

    // ---- epilogue (R2 direct stores): col=lane&15, row=(lane>>4)*4+reg ----
#pragma unroll
    for (int ni = 0; ni < 4; ++ni) {
        int col = bn + wn * 64 + ni * 16 + frow;
        float bv = bias[col];
#pragma unroll
        for (int mig = 0; mig < 8; ++mig) {
            int row0 = bm + wm * 128 + mig * 16 + (lane >> 4) * 4;
#pragma unroll
            for (int r = 0; r < 4; ++r)
                C[(size_t)(row0 + r) * NDIM + col] = acc[mig][ni][r] + bv;
        }
    }
#undef STAGE_A
#undef STAGE_B
#undef STAGE_TILE
#undef MFMA16
}

// ---------------- fallback ----------------

__global__ void fallback_gemm(const float* __restrict__ x, const float* __restrict__ W,
                              const float* __restrict__ b, float* __restrict__ out) {
    __shared__ float As[32][32];
    __shared__ float Bs[32][33];
    int tx = threadIdx.x, ty = threadIdx.y;
    int row = blockIdx.y * 32 + ty;
    int col = blockIdx.x * 32 + tx;
    float acc = 0.0f;
    for (int kt = 0; kt < KDIM; kt += 32) {
        As[ty][tx] = x[(size_t)row * KDIM + kt + tx];
        float w = W[(size_t)(kt + ty) * NDIM + col];
        Bs[ty][tx] = (w > 0.0f) ? 1.0f : ((w < 0.0f) ? -1.0f : 0.0f);
        __syncthreads();
#pragma unroll
        for (int k = 0; k < 32; ++k) acc += As[ty][k] * Bs[k][tx];
        __syncthreads();
    }
    out[(size_t)row * NDIM + col] = acc + b[col];
}

extern "C" void kernel_launch(void* const* d_in, const int* in_sizes, int n_in,
                              void* d_out, int out_size, void* d_ws, size_t ws_size,
                              hipStream_t stream) {
    const float* x = (const float*)d_in[0];
    const float* W = (const float*)d_in[1];
    const float* b = (const float*)d_in[2];
    float* out = (float*)d_out;

    const size_t need = (size_t)MDIM * KDIM * 2 + (size_t)KDIM * NDIM * 2;
    if (ws_size >= need) {
        unsigned short* xbf = (unsigned short*)d_ws;
        unsigned short* wqT = xbf + (size_t)MDIM * KDIM;
        prep_kernel<<<XBLKS + (NDIM / 64) * (KDIM / 64), 256, 0, stream>>>(x, W, xbf, wqT);
        gemm_bf16_bt<<<dim3(NDIM / BN, MDIM / BM), 512, 0, stream>>>(xbf, wqT, b, out);
    } else {
        fallback_gemm<<<dim3(NDIM / 32, MDIM / 32), dim3(32, 32), 0, stream>>>(x, W, b, out);
    }
}